// Round 2
// baseline (82.708 us; speedup 1.0000x reference)
//
#include <hip/hip_runtime.h>
#include <math.h>

constexpr int NG = 8192;   // genes
constexpr int NM = 256;    // sets
constexpr int NB = 32;     // batch
constexpr int KR = 64;     // k-range per k_mm block

// ws layout
// pind : float [NM][NG]   (+- ind^0.25, sign bit = neg flag)      8 MB
// Bpk  : float2[NB][NG]   (R^0.25, cf)                            2 MB
// sums : float [3][NB][NM]                                        96 KB
// sumN : float [NM]

__device__ __forceinline__ float sigmoidf(float x) { return 1.0f / (1.0f + expf(-x)); }

__device__ __forceinline__ float block_reduce(float v, float* red) {
  const int tid = threadIdx.x;
  red[tid] = v;
  __syncthreads();
  for (int off = 128; off > 0; off >>= 1) {
    if (tid < off) red[tid] += red[tid + off];
    __syncthreads();
  }
  float r = red[0];
  __syncthreads();
  return r;
}

// blocks 0..NM-1: per-set prep (thr, +-ind^a, sumN, zero sums slice)
// blocks NM..NM+NB-1: per-sample prep (cf scatter in LDS, pack (R^a, cf))
__global__ __launch_bounds__(256) void k_prep(const float* __restrict__ R,
                                              const int* __restrict__ S,
                                              const float* __restrict__ W,
                                              float* __restrict__ pind,
                                              float2* __restrict__ Bpk,
                                              float* __restrict__ sums,
                                              float* __restrict__ sumN) {
  __shared__ float lds[NG];       // 32 KB: ind stash / cf scatter target
  __shared__ float red[256];
  __shared__ float s_thr;
  const int tid = threadIdx.x;

  if (blockIdx.x < NM) {
    const int m = blockIdx.x;
    if (tid < 96) {  // zero the sums slice this m owns (before k_mm runs)
      const int c = tid >> 5, b = tid & 31;
      sums[c * NB * NM + b * NM + m] = 0.f;
    }
    const float4* w4 = reinterpret_cast<const float4*>(W + (size_t)m * NG);
    float s = 0.f;
    for (int i = tid; i < NG / 4; i += 256) {
      float4 v = w4[i];
      float o0 = sigmoidf(v.x), o1 = sigmoidf(v.y), o2 = sigmoidf(v.z), o3 = sigmoidf(v.w);
      reinterpret_cast<float4*>(lds)[i] = make_float4(o0, o1, o2, o3);
      s += o0 + o1 + o2 + o3;
    }
    s = block_reduce(s, red);
    if (tid == 0) s_thr = s * (0.3f / (float)NG);
    __syncthreads();
    const float thr = s_thr;
    float sn = 0.f;
    float4* dst = reinterpret_cast<float4*>(pind + (size_t)m * NG);
    for (int i = tid; i < NG / 4; i += 256) {
      float4 v4 = reinterpret_cast<const float4*>(lds)[i];
      float vv[4] = {v4.x, v4.y, v4.z, v4.w};
      float oo[4];
      #pragma unroll
      for (int j = 0; j < 4; ++j) {
        float v = vv[j];
        v = (v < thr) ? v * 0.01f : v;       // _set_indicators where()
        const float ia = sqrtf(sqrtf(v));    // ind^0.25 (>0, sign bit free)
        const bool ng = v < 0.1f;
        oo[j] = ng ? -ia : ia;
        sn += ng ? 1.f : 0.f;
      }
      dst[i] = make_float4(oo[0], oo[1], oo[2], oo[3]);
    }
    sn = block_reduce(sn, red);
    if (tid == 0) sumN[m] = sn;
  } else {
    const int b = blockIdx.x - NM;
    // scatter cumsum coefficient to original gene order: pos k -> (NG-k)
    const int4* s4 = reinterpret_cast<const int4*>(S + (size_t)b * NG);
    for (int i = tid; i < NG / 4; i += 256) {
      int4 g = s4[i];
      const int k = i * 4;
      lds[g.x] = (float)(NG - k);
      lds[g.y] = (float)(NG - (k + 1));
      lds[g.z] = (float)(NG - (k + 2));
      lds[g.w] = (float)(NG - (k + 3));
    }
    __syncthreads();
    const float4* r4 = reinterpret_cast<const float4*>(R + (size_t)b * NG);
    float4* dst = reinterpret_cast<float4*>(Bpk + (size_t)b * NG);
    for (int i = tid; i < NG / 4; i += 256) {
      float4 r = r4[i];
      float4 c = reinterpret_cast<const float4*>(lds)[i];
      dst[i * 2 + 0] = make_float4(sqrtf(sqrtf(r.x)), c.x, sqrtf(sqrtf(r.y)), c.y);
      dst[i * 2 + 1] = make_float4(sqrtf(sqrtf(r.z)), c.z, sqrtf(sqrtf(r.w)), c.w);
    }
  }
}

// Triple matmul over K with LDS tiling.
// grid = (NG/KR, NM/64); block 256 = 16 bgrp (TBt=2) x 16 mgrp (TMt=4)
__global__ __launch_bounds__(256) void k_mm(const float* __restrict__ pind,
                                            const float2* __restrict__ Bpk,
                                            float* __restrict__ sums) {
  __shared__ float  lm[KR][64];   // [k][m], m XOR-swizzled by k bits 4-5
  __shared__ float2 lb[KR][32];   // [k][b], b XOR-swizzled by k bits 3-4
  const int tid = threadIdx.x;
  const int k0 = blockIdx.x * KR;
  const int m0 = blockIdx.y * 64;

  {  // stage M-side: 64 rows x KR cols, transposed into LDS
    const int r = tid >> 2, seg = tid & 3;
    const float4* src = reinterpret_cast<const float4*>(pind + (size_t)(m0 + r) * NG + k0 + seg * 16);
    #pragma unroll
    for (int q = 0; q < 4; ++q) {
      float4 x = src[q];
      float xv[4] = {x.x, x.y, x.z, x.w};
      #pragma unroll
      for (int j = 0; j < 4; ++j) {
        const int kk = seg * 16 + q * 4 + j;
        lm[kk][r ^ (((kk >> 4) & 3) << 4)] = xv[j];
      }
    }
  }
  {  // stage B-side: 32 rows x KR cols of float2, transposed
    const int b = tid >> 3, kseg = (tid & 7) * 8;
    const float4* src = reinterpret_cast<const float4*>(Bpk + (size_t)b * NG + k0 + kseg);
    #pragma unroll
    for (int q = 0; q < 4; ++q) {
      float4 x = src[q];
      const int ka = kseg + q * 2, kb = ka + 1;
      lb[ka][b ^ (((ka >> 3) & 3) << 1)] = make_float2(x.x, x.y);
      lb[kb][b ^ (((kb >> 3) & 3) << 1)] = make_float2(x.z, x.w);
    }
  }
  __syncthreads();

  const int mgrp = tid & 15;   // m = m0 + mgrp*4 + mi
  const int bgrp = tid >> 4;   // b = bgrp*2 + bi
  float aA[2][4] = {}, aB[2][4] = {}, aC[2][4] = {};

  #pragma unroll 8
  for (int kk = 0; kk < KR; ++kk) {
    const float4 mv = *reinterpret_cast<const float4*>(&lm[kk][(mgrp * 4) ^ (((kk >> 4) & 3) << 4)]);
    const float4 bv = *reinterpret_cast<const float4*>(&lb[kk][(bgrp * 2) ^ (((kk >> 3) & 3) << 1)]);
    const float mvv[4] = {mv.x, mv.y, mv.z, mv.w};
    const float ra[2] = {bv.x, bv.z};
    const float cf[2] = {bv.y, bv.w};
    #pragma unroll
    for (int mi = 0; mi < 4; ++mi) {
      const float ia = fabsf(mvv[mi]);
      const float nf = (mvv[mi] < 0.f) ? 1.f : 0.f;
      #pragma unroll
      for (int bi = 0; bi < 2; ++bi) {
        const float wq = ra[bi] * ia;
        aA[bi][mi] += wq;
        aB[bi][mi] = fmaf(wq, cf[bi], aB[bi][mi]);
        aC[bi][mi] = fmaf(nf, cf[bi], aC[bi][mi]);
      }
    }
  }

  #pragma unroll
  for (int bi = 0; bi < 2; ++bi) {
    #pragma unroll
    for (int mi = 0; mi < 4; ++mi) {
      const int b = bgrp * 2 + bi;
      const int m = m0 + mgrp * 4 + mi;
      atomicAdd(&sums[0 * NB * NM + b * NM + m], aA[bi][mi]);
      atomicAdd(&sums[1 * NB * NM + b * NM + m], aB[bi][mi]);
      atomicAdd(&sums[2 * NB * NM + b * NM + m], aC[bi][mi]);
    }
  }
}

__global__ __launch_bounds__(256) void k_final(const float* __restrict__ sums,
                                               const float* __restrict__ sumN,
                                               float* __restrict__ out) {
  const int i = blockIdx.x * 256 + threadIdx.x;   // i = b*NM + m
  const int b = i >> 8, m = i & 255;
  const float sA = sums[0 * NB * NM + b * NM + m];
  const float sB = sums[1 * NB * NM + b * NM + m];
  const float sC = sums[2 * NB * NM + b * NM + m];
  const float sN = sumN[m];
  out[i] = (sB / (sA + 1e-10f) - sC / (sN + 1e-10f)) * (1.0f / (float)NG);
}

extern "C" void kernel_launch(void* const* d_in, const int* in_sizes, int n_in,
                              void* d_out, int out_size, void* d_ws, size_t ws_size,
                              hipStream_t stream) {
  const float* R = (const float*)d_in[0];
  const int*   S = (const int*)d_in[1];
  const float* W = (const float*)d_in[2];
  float* out = (float*)d_out;

  char* ws = (char*)d_ws;
  float*  pind = (float*)ws;                                           // 8 MB
  float2* Bpk  = (float2*)(ws + (size_t)NM * NG * 4);                  // 2 MB
  float*  sums = (float*)(ws + (size_t)NM * NG * 4 + (size_t)NB * NG * 8);
  float*  sumN = sums + 3 * NB * NM;

  k_prep <<<dim3(NM + NB), dim3(256), 0, stream>>>(R, S, W, pind, Bpk, sums, sumN);
  k_mm   <<<dim3(NG / KR, NM / 64), dim3(256), 0, stream>>>(pind, Bpk, sums);
  k_final<<<dim3(NB), dim3(256), 0, stream>>>(sums, sumN, out);
}

// Round 3
// 40.399 us; speedup vs baseline: 2.0473x; 2.0473x over previous
//
#include <hip/hip_runtime.h>
#include <math.h>

constexpr int NG  = 8192;        // genes
constexpr int NM  = 256;         // sets
constexpr int NB  = 32;          // batch
constexpr int KR  = 128;         // k-span per k_mm block
constexpr int NKB = NG / KR;     // 64 k-blocks
constexpr int MT  = 64;          // m-tile per k_mm block
constexpr int LMS = MT + 4;      // lm row stride (floats)
constexpr int LBS = NB + 2;      // lb row stride (float2)

// ws layout:
//   Bpk  : float2[NB][NG]            (R^0.25, cf)          2 MB
//   part : float [NKB][3][NB][NM]    split-K partials      6.3 MB
//   thr  : float [NM]
//   sumN : float [NM]

__device__ __forceinline__ float sigmoidf(float x) { return 1.0f / (1.0f + expf(-x)); }

__device__ __forceinline__ float block_reduce(float v, float* red) {
  const int tid = threadIdx.x;
  red[tid] = v;
  __syncthreads();
  for (int off = 128; off > 0; off >>= 1) {
    if (tid < off) red[tid] += red[tid + off];
    __syncthreads();
  }
  float r = red[0];
  __syncthreads();
  return r;
}

// blocks 0..NM-1   : thr[m] (mean sigmoid * 0.3) and sumN[m]
// blocks NM..NM+NB : cf scatter (LDS) + pack Bpk[b][g] = (R^0.25, cf)
__global__ __launch_bounds__(256) void k_prep(const float* __restrict__ R,
                                              const int* __restrict__ S,
                                              const float* __restrict__ W,
                                              float2* __restrict__ Bpk,
                                              float* __restrict__ thr,
                                              float* __restrict__ sumN) {
  __shared__ float lds[NG];       // 32 KB
  __shared__ float red[256];
  __shared__ float s_thr;
  const int tid = threadIdx.x;

  if (blockIdx.x < NM) {
    const int m = blockIdx.x;
    const float4* w4 = reinterpret_cast<const float4*>(W + (size_t)m * NG);
    float s = 0.f;
    for (int i = tid; i < NG / 4; i += 256) {
      float4 v = w4[i];
      float o0 = sigmoidf(v.x), o1 = sigmoidf(v.y), o2 = sigmoidf(v.z), o3 = sigmoidf(v.w);
      reinterpret_cast<float4*>(lds)[i] = make_float4(o0, o1, o2, o3);
      s += o0 + o1 + o2 + o3;
    }
    s = block_reduce(s, red);
    if (tid == 0) { s_thr = s * (0.3f / (float)NG); thr[m] = s * (0.3f / (float)NG); }
    __syncthreads();
    const float tm = s_thr;
    float sn = 0.f;
    for (int i = tid; i < NG / 4; i += 256) {
      float4 v4 = reinterpret_cast<const float4*>(lds)[i];
      float vv[4] = {v4.x, v4.y, v4.z, v4.w};
      #pragma unroll
      for (int j = 0; j < 4; ++j) {
        float v = vv[j];
        v = (v < tm) ? v * 0.01f : v;
        sn += (v < 0.1f) ? 1.f : 0.f;
      }
    }
    sn = block_reduce(sn, red);
    if (tid == 0) sumN[m] = sn;
  } else {
    const int b = blockIdx.x - NM;
    const int4* s4 = reinterpret_cast<const int4*>(S + (size_t)b * NG);
    for (int i = tid; i < NG / 4; i += 256) {
      int4 g = s4[i];
      const int k = i * 4;
      lds[g.x] = (float)(NG - k);
      lds[g.y] = (float)(NG - (k + 1));
      lds[g.z] = (float)(NG - (k + 2));
      lds[g.w] = (float)(NG - (k + 3));
    }
    __syncthreads();
    const float4* r4 = reinterpret_cast<const float4*>(R + (size_t)b * NG);
    float4* dst = reinterpret_cast<float4*>(Bpk + (size_t)b * NG);
    for (int i = tid; i < NG / 4; i += 256) {
      float4 r = r4[i];
      float4 c = reinterpret_cast<const float4*>(lds)[i];
      dst[i * 2 + 0] = make_float4(sqrtf(sqrtf(r.x)), c.x, sqrtf(sqrtf(r.y)), c.y);
      dst[i * 2 + 1] = make_float4(sqrtf(sqrtf(r.z)), c.z, sqrtf(sqrtf(r.w)), c.w);
    }
  }
}

// Split-K triple matmul, atomic-free. grid = (NKB, NM/MT); block 256.
// Thread tile: 4 m x 2 b. M-side (ia, sign=neg) computed from W at stage time.
__global__ __launch_bounds__(256) void k_mm(const float* __restrict__ W,
                                            const float* __restrict__ thr,
                                            const float2* __restrict__ Bpk,
                                            float* __restrict__ part) {
  __shared__ float  lm[KR][LMS];   // [k][m]  +-ia
  __shared__ float2 lb[KR][LBS];   // [k][b]  (r^a, cf)
  const int tid = threadIdx.x;
  const int kb  = blockIdx.x;
  const int k0  = kb * KR;
  const int m0  = blockIdx.y * MT;

  {  // stage M: wave w handles k-seg of 32 for all 64 rows (2-way-free LDS writes)
    const int r   = tid & 63;
    const int seg = tid >> 6;     // 0..3
    const float tm = thr[m0 + r];
    const float4* src = reinterpret_cast<const float4*>(W + (size_t)(m0 + r) * NG + k0 + seg * 32);
    #pragma unroll
    for (int q = 0; q < 8; ++q) {
      float4 v4 = src[q];
      float vv[4] = {v4.x, v4.y, v4.z, v4.w};
      #pragma unroll
      for (int j = 0; j < 4; ++j) {
        float v = sigmoidf(vv[j]);
        v = (v < tm) ? v * 0.01f : v;         // _set_indicators where()
        const float ia = sqrtf(sqrtf(v));     // ind^0.25
        lm[seg * 32 + q * 4 + j][r] = (v < 0.1f) ? -ia : ia;
      }
    }
  }
  {  // stage B: thread b = tid&31, kseg of 16
    const int b    = tid & 31;
    const int kseg = tid >> 5;    // 0..7
    const float4* src = reinterpret_cast<const float4*>(Bpk + (size_t)b * NG + k0 + kseg * 16);
    #pragma unroll
    for (int q = 0; q < 8; ++q) {
      float4 x = src[q];
      const int kk = kseg * 16 + q * 2;
      lb[kk][b]     = make_float2(x.x, x.y);
      lb[kk + 1][b] = make_float2(x.z, x.w);
    }
  }
  __syncthreads();

  const int mgrp = tid & 15;   // m = m0 + mgrp*4 + mi
  const int bgrp = tid >> 4;   // b = bgrp*2 + bi
  float aA[2][4] = {}, aB[2][4] = {}, aC[2][4] = {};

  #pragma unroll 8
  for (int kk = 0; kk < KR; ++kk) {
    const float4 mv = *reinterpret_cast<const float4*>(&lm[kk][mgrp * 4]);
    const float4 bv = *reinterpret_cast<const float4*>(&lb[kk][bgrp * 2]);
    const float mvv[4] = {mv.x, mv.y, mv.z, mv.w};
    const float ra[2]  = {bv.x, bv.z};
    const float cf[2]  = {bv.y, bv.w};
    #pragma unroll
    for (int mi = 0; mi < 4; ++mi) {
      const float ia = fabsf(mvv[mi]);
      const float nf = (mvv[mi] < 0.f) ? 1.f : 0.f;
      #pragma unroll
      for (int bi = 0; bi < 2; ++bi) {
        const float wq = ra[bi] * ia;
        aA[bi][mi] += wq;
        aB[bi][mi] = fmaf(wq, cf[bi], aB[bi][mi]);
        aC[bi][mi] = fmaf(nf, cf[bi], aC[bi][mi]);
      }
    }
  }

  // part[((kb*3 + c)*NB + b)*NM + m] — plain stores, no atomics
  #pragma unroll
  for (int bi = 0; bi < 2; ++bi) {
    const int b = bgrp * 2 + bi;
    #pragma unroll
    for (int mi = 0; mi < 4; ++mi) {
      const int m = m0 + mgrp * 4 + mi;
      part[((size_t)(kb * 3 + 0) * NB + b) * NM + m] = aA[bi][mi];
      part[((size_t)(kb * 3 + 1) * NB + b) * NM + m] = aB[bi][mi];
      part[((size_t)(kb * 3 + 2) * NB + b) * NM + m] = aC[bi][mi];
    }
  }
}

__global__ __launch_bounds__(256) void k_final(const float* __restrict__ part,
                                               const float* __restrict__ sumN,
                                               float* __restrict__ out) {
  const int i = blockIdx.x * 256 + threadIdx.x;   // i = b*NM + m
  const int b = i >> 8, m = i & 255;
  float sA = 0.f, sB = 0.f, sC = 0.f;
  #pragma unroll 4
  for (int kb = 0; kb < NKB; ++kb) {
    const float* p = part + ((size_t)(kb * 3) * NB + b) * NM + m;
    sA += p[0];
    sB += p[(size_t)NB * NM];
    sC += p[2 * (size_t)NB * NM];
  }
  const float sN = sumN[m];
  out[i] = (sB / (sA + 1e-10f) - sC / (sN + 1e-10f)) * (1.0f / (float)NG);
}

extern "C" void kernel_launch(void* const* d_in, const int* in_sizes, int n_in,
                              void* d_out, int out_size, void* d_ws, size_t ws_size,
                              hipStream_t stream) {
  const float* R = (const float*)d_in[0];
  const int*   S = (const int*)d_in[1];
  const float* W = (const float*)d_in[2];
  float* out = (float*)d_out;

  char* ws = (char*)d_ws;
  float2* Bpk  = (float2*)ws;                                   // 2 MB
  float*  part = (float*)(ws + (size_t)NB * NG * 8);            // 6.3 MB
  float*  thr  = part + (size_t)NKB * 3 * NB * NM;
  float*  sumN = thr + NM;

  k_prep <<<dim3(NM + NB), dim3(256), 0, stream>>>(R, S, W, Bpk, thr, sumN);
  k_mm   <<<dim3(NKB, NM / MT), dim3(256), 0, stream>>>(W, thr, Bpk, part);
  k_final<<<dim3(NB), dim3(256), 0, stream>>>(part, sumN, out);
}

// Round 4
// 34.120 us; speedup vs baseline: 2.4240x; 1.1840x over previous
//
#include <hip/hip_runtime.h>
#include <math.h>

constexpr int NG  = 8192;        // genes
constexpr int NM  = 256;         // sets
constexpr int NB  = 32;          // batch
constexpr int KR  = 64;          // k-span per k_mm block
constexpr int NKB = NG / KR;     // 128 k-blocks
constexpr int MT  = 64;          // m-tile per k_mm block
constexpr int LMS = MT + 4;      // lm row stride (floats)
constexpr int LBS = NB + 2;      // lb row stride (float2)

// ws layout:
//   Bpk  : float2[NB][NG]            (R^0.25, cf)          2 MB
//   part : float [NKB][3][NB][NM]    split-K partials      12 MB
//   thr  : float [NM]
//   sumN : float [NM]

__device__ __forceinline__ float sigmoidf(float x) {
  // 1/(1+exp(-x)) via v_exp_f32 + v_rcp_f32; large |x| saturates correctly.
  return __builtin_amdgcn_rcpf(1.0f + __builtin_amdgcn_exp2f(x * -1.442695041f));
}
__device__ __forceinline__ float qrtf(float x) {   // x^0.25
  return __builtin_amdgcn_sqrtf(__builtin_amdgcn_sqrtf(x));
}

__device__ __forceinline__ float block_reduce(float v, float* red) {
  const int tid = threadIdx.x;
  red[tid] = v;
  __syncthreads();
  for (int off = 128; off > 0; off >>= 1) {
    if (tid < off) red[tid] += red[tid + off];
    __syncthreads();
  }
  float r = red[0];
  __syncthreads();
  return r;
}

// blocks 0..NM-1   : thr[m] (mean sigmoid * 0.3) and sumN[m]
// blocks NM..NM+NB : cf scatter (LDS) + pack Bpk[b][g] = (R^0.25, cf)
__global__ __launch_bounds__(256) void k_prep(const float* __restrict__ R,
                                              const int* __restrict__ S,
                                              const float* __restrict__ W,
                                              float2* __restrict__ Bpk,
                                              float* __restrict__ thr,
                                              float* __restrict__ sumN) {
  __shared__ float lds[NG];       // 32 KB
  __shared__ float red[256];
  __shared__ float s_thr;
  const int tid = threadIdx.x;

  if (blockIdx.x < NM) {
    const int m = blockIdx.x;
    const float4* w4 = reinterpret_cast<const float4*>(W + (size_t)m * NG);
    float s = 0.f;
    for (int i = tid; i < NG / 4; i += 256) {
      float4 v = w4[i];
      float o0 = sigmoidf(v.x), o1 = sigmoidf(v.y), o2 = sigmoidf(v.z), o3 = sigmoidf(v.w);
      reinterpret_cast<float4*>(lds)[i] = make_float4(o0, o1, o2, o3);
      s += o0 + o1 + o2 + o3;
    }
    s = block_reduce(s, red);
    if (tid == 0) { s_thr = s * (0.3f / (float)NG); thr[m] = s_thr; }
    __syncthreads();
    const float tm = s_thr;
    float sn = 0.f;
    for (int i = tid; i < NG / 4; i += 256) {
      float4 v4 = reinterpret_cast<const float4*>(lds)[i];
      float vv[4] = {v4.x, v4.y, v4.z, v4.w};
      #pragma unroll
      for (int j = 0; j < 4; ++j) {
        float v = vv[j];
        v = (v < tm) ? v * 0.01f : v;
        sn += (v < 0.1f) ? 1.f : 0.f;
      }
    }
    sn = block_reduce(sn, red);
    if (tid == 0) sumN[m] = sn;
  } else {
    const int b = blockIdx.x - NM;
    const int4* s4 = reinterpret_cast<const int4*>(S + (size_t)b * NG);
    for (int i = tid; i < NG / 4; i += 256) {
      int4 g = s4[i];
      const int k = i * 4;
      lds[g.x] = (float)(NG - k);
      lds[g.y] = (float)(NG - (k + 1));
      lds[g.z] = (float)(NG - (k + 2));
      lds[g.w] = (float)(NG - (k + 3));
    }
    __syncthreads();
    const float4* r4 = reinterpret_cast<const float4*>(R + (size_t)b * NG);
    float4* dst = reinterpret_cast<float4*>(Bpk + (size_t)b * NG);
    for (int i = tid; i < NG / 4; i += 256) {
      float4 r = r4[i];
      float4 c = reinterpret_cast<const float4*>(lds)[i];
      dst[i * 2 + 0] = make_float4(qrtf(r.x), c.x, qrtf(r.y), c.y);
      dst[i * 2 + 1] = make_float4(qrtf(r.z), c.z, qrtf(r.w), c.w);
    }
  }
}

// Split-K triple matmul, atomic-free. grid = (NKB, NM/MT); block 256.
// Thread tile: 4 m x 2 b. M-side (ia, sign=neg) computed from W at stage time.
__global__ __launch_bounds__(256) void k_mm(const float* __restrict__ W,
                                            const float* __restrict__ thr,
                                            const float2* __restrict__ Bpk,
                                            float* __restrict__ part) {
  __shared__ float  lm[KR][LMS];   // [k][m]  +-ia   (~17 KB)
  __shared__ float2 lb[KR][LBS];   // [k][b]  (r^a, cf)  (~17 KB)
  const int tid = threadIdx.x;
  const int kb  = blockIdx.x;
  const int k0  = kb * KR;
  const int m0  = blockIdx.y * MT;

  {  // stage M: wave w handles k-seg of 16 for all 64 rows
    const int r   = tid & 63;
    const int seg = tid >> 6;     // 0..3
    const float tm = thr[m0 + r];
    const float4* src = reinterpret_cast<const float4*>(W + (size_t)(m0 + r) * NG + k0 + seg * 16);
    #pragma unroll
    for (int q = 0; q < 4; ++q) {
      float4 v4 = src[q];
      float vv[4] = {v4.x, v4.y, v4.z, v4.w};
      #pragma unroll
      for (int j = 0; j < 4; ++j) {
        float v = sigmoidf(vv[j]);
        v = (v < tm) ? v * 0.01f : v;         // _set_indicators where()
        const float ia = qrtf(v);             // ind^0.25
        lm[seg * 16 + q * 4 + j][r] = (v < 0.1f) ? -ia : ia;
      }
    }
  }
  {  // stage B: thread b = tid&31, kseg of 8
    const int b    = tid & 31;
    const int kseg = tid >> 5;    // 0..7
    const float4* src = reinterpret_cast<const float4*>(Bpk + (size_t)b * NG + k0 + kseg * 8);
    #pragma unroll
    for (int q = 0; q < 4; ++q) {
      float4 x = src[q];
      const int kk = kseg * 8 + q * 2;
      lb[kk][b]     = make_float2(x.x, x.y);
      lb[kk + 1][b] = make_float2(x.z, x.w);
    }
  }
  __syncthreads();

  const int mgrp = tid & 15;   // m = m0 + mgrp*4 + mi
  const int bgrp = tid >> 4;   // b = bgrp*2 + bi
  float aA[2][4] = {}, aB[2][4] = {}, aC[2][4] = {};

  #pragma unroll 8
  for (int kk = 0; kk < KR; ++kk) {
    const float4 mv = *reinterpret_cast<const float4*>(&lm[kk][mgrp * 4]);
    const float4 bv = *reinterpret_cast<const float4*>(&lb[kk][bgrp * 2]);
    const float mvv[4] = {mv.x, mv.y, mv.z, mv.w};
    const float ra[2]  = {bv.x, bv.z};
    const float cf[2]  = {bv.y, bv.w};
    #pragma unroll
    for (int mi = 0; mi < 4; ++mi) {
      const float ia = fabsf(mvv[mi]);
      const float nf = (mvv[mi] < 0.f) ? 1.f : 0.f;
      #pragma unroll
      for (int bi = 0; bi < 2; ++bi) {
        const float wq = ra[bi] * ia;
        aA[bi][mi] += wq;
        aB[bi][mi] = fmaf(wq, cf[bi], aB[bi][mi]);
        aC[bi][mi] = fmaf(nf, cf[bi], aC[bi][mi]);
      }
    }
  }

  // part[((kb*3 + c)*NB + b)*NM + m] — plain stores, no atomics
  #pragma unroll
  for (int bi = 0; bi < 2; ++bi) {
    const int b = bgrp * 2 + bi;
    #pragma unroll
    for (int mi = 0; mi < 4; ++mi) {
      const int m = m0 + mgrp * 4 + mi;
      part[((size_t)(kb * 3 + 0) * NB + b) * NM + m] = aA[bi][mi];
      part[((size_t)(kb * 3 + 1) * NB + b) * NM + m] = aB[bi][mi];
      part[((size_t)(kb * 3 + 2) * NB + b) * NM + m] = aC[bi][mi];
    }
  }
}

// grid 256: block = (b, m-chunk of 32); tid = kg(8) x ml(32); LDS tree over kg.
__global__ __launch_bounds__(256) void k_final(const float* __restrict__ part,
                                               const float* __restrict__ sumN,
                                               float* __restrict__ out) {
  __shared__ float rA[256], rB[256], rC[256];
  const int tid = threadIdx.x;
  const int b   = blockIdx.x >> 3;
  const int mc  = blockIdx.x & 7;
  const int ml  = tid & 31;
  const int kg  = tid >> 5;             // 0..7
  const int m   = mc * 32 + ml;

  float sA = 0.f, sB = 0.f, sC = 0.f;
  #pragma unroll 4
  for (int t = 0; t < NKB / 8; ++t) {
    const int kb = kg * (NKB / 8) + t;
    const float* p = part + ((size_t)(kb * 3) * NB + b) * NM + m;
    sA += p[0];
    sB += p[(size_t)NB * NM];
    sC += p[2 * (size_t)NB * NM];
  }
  rA[tid] = sA; rB[tid] = sB; rC[tid] = sC;
  __syncthreads();
  #pragma unroll
  for (int off = 128; off >= 32; off >>= 1) {
    if (tid < off) { rA[tid] += rA[tid + off]; rB[tid] += rB[tid + off]; rC[tid] += rC[tid + off]; }
    __syncthreads();
  }
  if (tid < 32) {
    const float sN = sumN[m];
    out[(size_t)b * NM + m] = (rB[tid] / (rA[tid] + 1e-10f) - rC[tid] / (sN + 1e-10f)) * (1.0f / (float)NG);
  }
}

extern "C" void kernel_launch(void* const* d_in, const int* in_sizes, int n_in,
                              void* d_out, int out_size, void* d_ws, size_t ws_size,
                              hipStream_t stream) {
  const float* R = (const float*)d_in[0];
  const int*   S = (const int*)d_in[1];
  const float* W = (const float*)d_in[2];
  float* out = (float*)d_out;

  char* ws = (char*)d_ws;
  float2* Bpk  = (float2*)ws;                                   // 2 MB
  float*  part = (float*)(ws + (size_t)NB * NG * 8);            // 12 MB
  float*  thr  = part + (size_t)NKB * 3 * NB * NM;
  float*  sumN = thr + NM;

  k_prep <<<dim3(NM + NB), dim3(256), 0, stream>>>(R, S, W, Bpk, thr, sumN);
  k_mm   <<<dim3(NKB, NM / MT), dim3(256), 0, stream>>>(W, thr, Bpk, part);
  k_final<<<dim3(NB * 8), dim3(256), 0, stream>>>(part, sumN, out);
}